// Round 1
// baseline (235.647 us; speedup 1.0000x reference)
//
#include <hip/hip_runtime.h>

typedef unsigned short u16;
typedef __bf16 bf16x8 __attribute__((ext_vector_type(8)));
typedef float floatx4 __attribute__((ext_vector_type(4)));

#define B_   2
#define T_   1024
#define DIM_ 1024
#define H_   8
#define DH_  64
#define E_   5

// c1 column layout: [0,512) q | [512,1024) k | [1024,3584) vexp (h,e,dh)
#define N1   3584
#define M_   2048
#define KOUT 2560   // (h,e,c) contraction dim of output GEMM

__device__ __forceinline__ u16 f2bf(float f) {
  union { float f; unsigned u; } v; v.f = f;
  unsigned r = v.u + 0x7FFFu + ((v.u >> 16) & 1u);
  return (u16)(r >> 16);
}
__device__ __forceinline__ float bf2f(u16 h) {
  union { unsigned u; float f; } v; v.u = ((unsigned)h) << 16;
  return v.f;
}

__device__ __forceinline__ void async_cp16(const void* g, void* l) {
  __builtin_amdgcn_global_load_lds(
      (const __attribute__((address_space(1))) unsigned int*)g,
      (__attribute__((address_space(3))) unsigned int*)l, 16, 0, 0);
}

// ---------------- layout kernels ----------------

__global__ void cvt_x_kernel(const float* __restrict__ x, u16* __restrict__ xb) {
  int i = blockIdx.x * 256 + threadIdx.x;            // 524288 float4 groups
  float4 v = ((const float4*)x)[i];
  union { u16 s[4]; uint2 u; } o;
  o.s[0] = f2bf(v.x); o.s[1] = f2bf(v.y); o.s[2] = f2bf(v.z); o.s[3] = f2bf(v.w);
  ((uint2*)xb)[i] = o.u;
}

// W [1024][N] fp32 -> WT[(n_ofs+n)][1024] bf16  (32x32 LDS tile transpose)
__global__ __launch_bounds__(256)
void transpose_w_kernel(const float* __restrict__ W, u16* __restrict__ WT,
                        int N, int n_ofs) {
  __shared__ float tile[32][33];
  int k0 = blockIdx.x * 32, n0 = blockIdx.y * 32;
  int tx = threadIdx.x & 31, ty = threadIdx.x >> 5;  // 8 rows per pass
  #pragma unroll
  for (int i = 0; i < 32; i += 8)
    tile[ty + i][tx] = W[(size_t)(k0 + ty + i) * N + n0 + tx];
  __syncthreads();
  #pragma unroll
  for (int i = 0; i < 32; i += 8)
    WT[(size_t)(n_ofs + n0 + ty + i) * 1024 + k0 + tx] = f2bf(tile[tx][ty + i]);
}

// Wo [H,E,DIM,DH] fp32 -> WoT [d][(h*E+e)*64+c] bf16 (contiguous-run gather)
__global__ void build_WoT_kernel(const float* __restrict__ Wo, u16* __restrict__ WoT) {
  int i = blockIdx.x * 256 + threadIdx.x;            // 655360 = 2560*1024/4
  int c4 = i & 15;
  int t  = i >> 4;
  int d  = t / 40;
  int he = t - d * 40;
  float4 v = *(const float4*)(Wo + ((size_t)(he * 1024 + d) * 64 + c4 * 4));
  union { u16 s[4]; uint2 u; } o;
  o.s[0] = f2bf(v.x); o.s[1] = f2bf(v.y); o.s[2] = f2bf(v.z); o.s[3] = f2bf(v.w);
  *(uint2*)(WoT + (size_t)d * KOUT + he * 64 + c4 * 4) = o.u;
}

// v_row [bt][h*64+dh] bf16 -> vT [(b*8+h)*64+dh][t] bf16
__global__ __launch_bounds__(256)
void tr_v_kernel(const u16* __restrict__ v_row, u16* __restrict__ vT) {
  __shared__ u16 tile[32][33];
  int t0 = blockIdx.x * 32, d0 = blockIdx.y * 32;
  int bh = blockIdx.z;
  int b = bh >> 3, h = bh & 7;
  int tx = threadIdx.x & 31, ty = threadIdx.x >> 5;
  #pragma unroll
  for (int i = 0; i < 32; i += 8)
    tile[ty + i][tx] = v_row[(size_t)(b * T_ + t0 + ty + i) * 512 + h * 64 + d0 + tx];
  __syncthreads();
  #pragma unroll
  for (int i = 0; i < 32; i += 8)
    vT[(size_t)((b * H_ + h) * DH_ + d0 + ty + i) * T_ + t0 + tx] = tile[tx][ty + i];
}

// ---------------- MFMA GEMM (C = A @ B^T), A [M][K] bf16, B [N][K] bf16 ----------------

template <int BN, int WAVES_N, int MT, bool OUT_BF16>
__global__ __launch_bounds__(256, 2)
void gemm_bt_kernel(const u16* __restrict__ A, const u16* __restrict__ Bm,
                    void* __restrict__ Cv, int N, int Kd) {
  constexpr int BM = 128, BK = 32;
  __shared__ __align__(16) u16 As[BM * BK];
  __shared__ __align__(16) u16 Bs[BN * BK];
  const int tid = threadIdx.x;
  const int w = tid >> 6, lane = tid & 63;
  const int ln15 = lane & 15, quad = lane >> 4;
  const int bm0 = blockIdx.x * BM, bn0 = blockIdx.y * BN;
  const int wm = w / WAVES_N, wn = w % WAVES_N;
  const int arow = lane >> 2, aoff = (lane & 3) * 8;

  floatx4 acc[MT][4];
  #pragma unroll
  for (int i = 0; i < MT; ++i)
    #pragma unroll
    for (int j = 0; j < 4; ++j) acc[i][j] = (floatx4){0.f, 0.f, 0.f, 0.f};

  for (int k0 = 0; k0 < Kd; k0 += BK) {
    __syncthreads();
    #pragma unroll
    for (int i = w * 2; i < w * 2 + 2; ++i)   // A: 8 instrs of 16 rows
      async_cp16(A + (size_t)(bm0 + i * 16 + arow) * Kd + k0 + aoff,
                 (char*)As + i * 1024);
    constexpr int BIW = (BN / 16) / 4;        // B instrs per wave (2 or 1)
    #pragma unroll
    for (int i = w * BIW; i < (w + 1) * BIW; ++i)
      async_cp16(Bm + (size_t)(bn0 + i * 16 + arow) * Kd + k0 + aoff,
                 (char*)Bs + i * 1024);
    __builtin_amdgcn_s_waitcnt(0);
    __syncthreads();

    bf16x8 af[MT], bf[4];
    #pragma unroll
    for (int mt = 0; mt < MT; ++mt)
      af[mt] = *(const bf16x8*)(As + (wm * (MT * 16) + mt * 16 + ln15) * BK + quad * 8);
    #pragma unroll
    for (int nt = 0; nt < 4; ++nt)
      bf[nt] = *(const bf16x8*)(Bs + (wn * 64 + nt * 16 + ln15) * BK + quad * 8);
    #pragma unroll
    for (int mt = 0; mt < MT; ++mt)
      #pragma unroll
      for (int nt = 0; nt < 4; ++nt)
        acc[mt][nt] = __builtin_amdgcn_mfma_f32_16x16x32_bf16(af[mt], bf[nt], acc[mt][nt], 0, 0, 0);
  }

  #pragma unroll
  for (int mt = 0; mt < MT; ++mt)
    #pragma unroll
    for (int nt = 0; nt < 4; ++nt)
      #pragma unroll
      for (int r = 0; r < 4; ++r) {
        int m = bm0 + wm * (MT * 16) + mt * 16 + quad * 4 + r;
        int n = bn0 + wn * 64 + nt * 16 + ln15;
        float v = acc[mt][nt][r];
        if (OUT_BF16) ((u16*)Cv)[(size_t)m * N + n] = f2bf(v);
        else          ((float*)Cv)[(size_t)m * N + n] = v;
      }
}

// ---------------- routing: fp32 logits + sigmoid + top-k + V mix ----------------

__global__ __launch_bounds__(128)
void routing_kernel(const float* __restrict__ x, const float* __restrict__ Ws,
                    const float* __restrict__ Wd, const u16* __restrict__ c1,
                    float* __restrict__ sdg, u16* __restrict__ v_row) {
  __shared__ float xs[1024];
  __shared__ float lg[80];
  __shared__ float ssg[H_][E_];
  const int bt = blockIdx.x;
  const int tid = threadIdx.x;

  const float4* xsrc = (const float4*)(x + (size_t)bt * 1024);
  float4* xd = (float4*)xs;
  for (int i = tid; i < 256; i += 128) xd[i] = xsrc[i];
  __syncthreads();

  if (tid < 80) {
    const float* Wp = (tid < 40) ? Ws : Wd;
    const int c = (tid < 40) ? tid : tid - 40;
    float acc = 0.f;
    for (int k = 0; k < 1024; k += 4) {
      float4 xv = *(const float4*)(xs + k);
      acc = fmaf(xv.x, Wp[(k + 0) * 40 + c], acc);
      acc = fmaf(xv.y, Wp[(k + 1) * 40 + c], acc);
      acc = fmaf(xv.z, Wp[(k + 2) * 40 + c], acc);
      acc = fmaf(xv.w, Wp[(k + 3) * 40 + c], acc);
    }
    lg[tid] = acc;
  }
  __syncthreads();

  if (tid < 16) {
    const int h = tid >> 1, which = tid & 1;
    float v[E_]; bool sel[E_];
    #pragma unroll
    for (int e = 0; e < E_; ++e) {
      float z = lg[which * 40 + h * E_ + e];
      v[e] = 1.f / (1.f + __expf(-z));
      sel[e] = false;
    }
    #pragma unroll
    for (int it = 0; it < 3; ++it) {        // iterative argmax, first-index ties
      int bi = 0; float bv = -1e30f;
      #pragma unroll
      for (int e = 0; e < E_; ++e)
        if (!sel[e] && v[e] > bv) { bv = v[e]; bi = e; }
      sel[bi] = true;
    }
    if (which == 0) {
      #pragma unroll
      for (int e = 0; e < E_; ++e) ssg[h][e] = sel[e] ? v[e] : 0.f;
    } else {
      #pragma unroll
      for (int e = 0; e < E_; ++e)
        sdg[(size_t)bt * 40 + h * E_ + e] = sel[e] ? 1.f : 0.f;
    }
  }
  __syncthreads();

  for (int idx = tid; idx < 512; idx += 128) {
    const int h = idx >> 6, dh = idx & 63;
    const u16* ve = c1 + (size_t)bt * N1 + 1024 + h * (E_ * 64) + dh;
    float s = 0.f;
    #pragma unroll
    for (int e = 0; e < E_; ++e) s = fmaf(ssg[h][e], bf2f(ve[e * 64]), s);
    v_row[(size_t)bt * 512 + h * 64 + dh] = f2bf(s);
  }
}

// ---------------- MFMA flash attention + gated A-write ----------------

__global__ __launch_bounds__(256, 2)
void attn_kernel(const u16* __restrict__ c1, const u16* __restrict__ vT,
                 const float* __restrict__ sdg, u16* __restrict__ Ab) {
  __shared__ __align__(16) u16 Qs[64 * 64];
  __shared__ __align__(16) u16 Ks[64 * 64];
  __shared__ __align__(16) u16 Vs[64 * 64];
  __shared__ __align__(16) u16 Ps[64 * 72];   // +8 pad per row
  const int qi = blockIdx.x;                   // 0..15 (64-row q tile)
  const int bh = blockIdx.y;
  const int b = bh >> 3, h = bh & 7;
  const int tid = threadIdx.x;
  const int w = tid >> 6, lane = tid & 63;
  const int ln15 = lane & 15, quad = lane >> 4;
  const int q0 = qi * 64;
  const int r8 = lane >> 3, o8 = (lane & 7) * 8;

  #pragma unroll
  for (int i = w * 2; i < w * 2 + 2; ++i) {
    int r = i * 8 + r8;
    async_cp16(c1 + (size_t)(b * T_ + q0 + r) * N1 + h * DH_ + o8, (char*)Qs + i * 1024);
  }

  floatx4 O[4];
  float m_st[4], l_st[4];
  #pragma unroll
  for (int j = 0; j < 4; ++j) {
    O[j] = (floatx4){0.f, 0.f, 0.f, 0.f};
    m_st[j] = -3e38f; l_st[j] = 0.f;
  }
  const int qrow = q0 + w * 16 + quad * 4;

  for (int kt = 0; kt <= qi; ++kt) {
    const int tk0 = kt * 64;
    __syncthreads();
    #pragma unroll
    for (int i = w * 2; i < w * 2 + 2; ++i) {
      int r = i * 8 + r8;
      async_cp16(c1 + (size_t)(b * T_ + tk0 + r) * N1 + 512 + h * DH_ + o8, (char*)Ks + i * 1024);
      async_cp16(vT + (size_t)((b * H_ + h) * DH_ + r) * T_ + tk0 + o8, (char*)Vs + i * 1024);
    }
    __builtin_amdgcn_s_waitcnt(0);
    __syncthreads();

    floatx4 S[4];
    #pragma unroll
    for (int nt = 0; nt < 4; ++nt) S[nt] = (floatx4){0.f, 0.f, 0.f, 0.f};
    #pragma unroll
    for (int ks = 0; ks < 2; ++ks) {
      bf16x8 a = *(const bf16x8*)(Qs + (w * 16 + ln15) * 64 + ks * 32 + quad * 8);
      #pragma unroll
      for (int nt = 0; nt < 4; ++nt) {
        bf16x8 bv = *(const bf16x8*)(Ks + (nt * 16 + ln15) * 64 + ks * 32 + quad * 8);
        S[nt] = __builtin_amdgcn_mfma_f32_16x16x32_bf16(a, bv, S[nt], 0, 0, 0);
      }
    }

    float p[4][4], rmax[4], alpha[4], rsum[4];
    #pragma unroll
    for (int r = 0; r < 4; ++r) rmax[r] = -3e38f;
    #pragma unroll
    for (int nt = 0; nt < 4; ++nt) {
      int col = tk0 + nt * 16 + ln15;
      #pragma unroll
      for (int r = 0; r < 4; ++r) {
        float s = S[nt][r] * 0.125f;          // DH^-0.5
        if (col > qrow + r) s = -3e38f;        // causal
        p[nt][r] = s;
        rmax[r] = fmaxf(rmax[r], s);
      }
    }
    #pragma unroll
    for (int r = 0; r < 4; ++r) {
      #pragma unroll
      for (int off = 1; off < 16; off <<= 1)
        rmax[r] = fmaxf(rmax[r], __shfl_xor(rmax[r], off));
      float mn = fmaxf(m_st[r], rmax[r]);
      alpha[r] = __expf(m_st[r] - mn);
      m_st[r] = mn;
      rsum[r] = 0.f;
    }
    #pragma unroll
    for (int nt = 0; nt < 4; ++nt)
      #pragma unroll
      for (int r = 0; r < 4; ++r) {
        float e = __expf(p[nt][r] - m_st[r]);
        p[nt][r] = e;
        rsum[r] += e;
      }
    #pragma unroll
    for (int r = 0; r < 4; ++r) {
      #pragma unroll
      for (int off = 1; off < 16; off <<= 1)
        rsum[r] += __shfl_xor(rsum[r], off);
      l_st[r] = l_st[r] * alpha[r] + rsum[r];
    }
    #pragma unroll
    for (int nt = 0; nt < 4; ++nt)
      #pragma unroll
      for (int r = 0; r < 4; ++r) O[nt][r] *= alpha[r];
    #pragma unroll
    for (int nt = 0; nt < 4; ++nt)
      #pragma unroll
      for (int r = 0; r < 4; ++r)
        Ps[(w * 16 + quad * 4 + r) * 72 + nt * 16 + ln15] = f2bf(p[nt][r]);
    __syncthreads();

    #pragma unroll
    for (int ks = 0; ks < 2; ++ks) {
      bf16x8 a = *(const bf16x8*)(Ps + (w * 16 + ln15) * 72 + ks * 32 + quad * 8);
      #pragma unroll
      for (int nt = 0; nt < 4; ++nt) {
        bf16x8 bv = *(const bf16x8*)(Vs + (nt * 16 + ln15) * 64 + ks * 32 + quad * 8);
        O[nt] = __builtin_amdgcn_mfma_f32_16x16x32_bf16(a, bv, O[nt], 0, 0, 0);
      }
    }
  }

  #pragma unroll
  for (int r = 0; r < 4; ++r) l_st[r] = 1.f / l_st[r];
  #pragma unroll
  for (int nt = 0; nt < 4; ++nt) {
    int dh = nt * 16 + ln15;
    #pragma unroll
    for (int r = 0; r < 4; ++r) {
      int q = qrow + r;
      size_t bt = (size_t)b * T_ + q;
      float o = O[nt][r] * l_st[r];
      #pragma unroll
      for (int e = 0; e < E_; ++e) {
        float g = sdg[bt * 40 + h * E_ + e];
        Ab[bt * KOUT + (h * E_ + e) * 64 + dh] = f2bf(g * o);
      }
    }
  }
}

// ---------------- launch ----------------

extern "C" void kernel_launch(void* const* d_in, const int* in_sizes, int n_in,
                              void* d_out, int out_size, void* d_ws, size_t ws_size,
                              hipStream_t stream) {
  const float* x  = (const float*)d_in[0];
  const float* Wq = (const float*)d_in[1];
  const float* Wk = (const float*)d_in[2];
  const float* Wv = (const float*)d_in[3];
  const float* Ws = (const float*)d_in[4];
  const float* Wd = (const float*)d_in[5];
  const float* Wo = (const float*)d_in[6];
  float* out = (float*)d_out;

  char* ws = (char*)d_ws;
  u16*   xb   = (u16*)(ws + 0);            //  4,194,304
  u16*   WT   = (u16*)(ws + 4194304);      //  7,340,032
  u16*   WoT  = (u16*)(ws + 11534336);     //  5,242,880
  u16*   c1   = (u16*)(ws + 16777216);     // 14,680,064
  float* sdg  = (float*)(ws + 31457280);   //    327,680
  u16*   vrow = (u16*)(ws + 31784960);     //  2,097,152
  u16*   vT   = (u16*)(ws + 33882112);     //  2,097,152
  u16*   Ab   = (u16*)(ws + 35979264);     // 10,485,760 (end 46,465,024)

  cvt_x_kernel<<<2048, 256, 0, stream>>>(x, xb);
  transpose_w_kernel<<<dim3(32, 16), 256, 0, stream>>>(Wq, WT, 512, 0);
  transpose_w_kernel<<<dim3(32, 16), 256, 0, stream>>>(Wk, WT, 512, 512);
  transpose_w_kernel<<<dim3(32, 80), 256, 0, stream>>>(Wv, WT, 2560, 1024);
  build_WoT_kernel<<<2560, 256, 0, stream>>>(Wo, WoT);

  // c1 = xb @ WT^T : M=2048, N=3584, K=1024
  gemm_bt_kernel<128, 2, 4, true><<<dim3(16, 28), 256, 0, stream>>>(xb, WT, c1, N1, 1024);

  routing_kernel<<<2048, 128, 0, stream>>>(x, Ws, Wd, c1, sdg, vrow);
  tr_v_kernel<<<dim3(32, 2, 16), 256, 0, stream>>>(vrow, vT);

  attn_kernel<<<dim3(16, 16), 256, 0, stream>>>(c1, vT, sdg, Ab);

  // out = Ab @ WoT^T : M=2048, N=1024, K=2560
  gemm_bt_kernel<64, 1, 2, false><<<dim3(16, 16), 256, 0, stream>>>(Ab, WoT, out, 1024, KOUT);
}